// Round 3
// baseline (316.038 us; speedup 1.0000x reference)
//
#include <hip/hip_runtime.h>

#define MAXLEN 100
#define HDIM 64
#define SEGW 8            // segments per wave (one 64-thread block = one wave)
#define HSTR 72           // ushorts per h row (144 B: 16B-aligned, conflict-free)
#define L2E 1.44269504f

typedef __attribute__((ext_vector_type(8))) short bf16x8;
typedef __attribute__((ext_vector_type(4))) float f32x4;

// RNE f32x2 -> packed bf16x2 in one instruction (no builtin on gfx950).
__device__ __forceinline__ unsigned cvtpk(float a, float b) {
    unsigned r;
    asm("v_cvt_pk_bf16_f32 %0, %1, %2" : "=v"(r) : "v"(a), "v"(b));
    return r;
}
__device__ __forceinline__ bf16x8 pack8(f32x4 a, f32x4 b) {
    union { unsigned u[4]; bf16x8 v; } c;
    c.u[0] = cvtpk(a[0], a[1]); c.u[1] = cvtpk(a[2], a[3]);
    c.u[2] = cvtpk(b[0], b[1]); c.u[3] = cvtpk(b[2], b[3]);
    return c.v;
}
// Activations on PRE-SCALED pre-activations: -L2E (resp -2*L2E for gate g)
// is folded into the bf16 weights; the scaled bias is the MFMA C-seed.
__device__ __forceinline__ float sig_pre(float a) {     // a = -L2E*z
    return __builtin_amdgcn_rcpf(1.0f + __builtin_amdgcn_exp2f(a));
}
__device__ __forceinline__ float tanh_pre(float a) {    // a = -2*L2E*z
    return fmaf(2.0f, __builtin_amdgcn_rcpf(1.0f + __builtin_amdgcn_exp2f(a)), -1.0f);
}
__device__ __forceinline__ float tanh_p(float v) {      // v in true scale
    return fmaf(2.0f, __builtin_amdgcn_rcpf(1.0f + __builtin_amdgcn_exp2f(v * (-2.0f * L2E))), -1.0f);
}

// One wave per 8 segments, FULL hidden dim per wave, full weights in VGPRs
// (256 regs), h exchanged through a private 1.2 KB LDS slab with same-wave
// DS ordering -> ZERO barriers in the step loop. 1024 blocks x 64 threads =
// 1024 waves = exactly 1 wave/SIMD machine-wide (VGPR ~450 forces that
// occupancy anyway). No pre-pass: wall time = longest segment (~100 steps)
// regardless of segment placement, so the length-sort (R1/R2) is pure
// dispatch overhead -> deleted. Single dispatch total.
//
// MFMA 16x16x32 layout (proven in prior kernels):
//   A-frag: lane holds A[row=l15][k=quad*8..+8] per 32-wide k-tile.
//   B-frag: lane holds W[outcol=ct*16+l15][k=quad*8..+8].
//   C: col=l15 (hid within ct), row=quad*4+reg (seg domain).
// Real A/C rows are {4k, 4k+1}; rows {4k+2,4k+3} alias the same segs
// (harmless: C rows are independent, garbage rows are never read).
// => per lane: C regs 0,1 real (segs quad*2, quad*2+1), regs 2,3 ignored.
__global__ __launch_bounds__(64, 1)
void lstm_wave_kernel(const float* __restrict__ x,
                      const float* __restrict__ Wih,
                      const float* __restrict__ Whh,
                      const float* __restrict__ bih,
                      const float* __restrict__ bhh,
                      const int* __restrict__ index,
                      float* __restrict__ out, int N, int B) {
    const int lane = threadIdx.x;
    const int l15  = lane & 15;
    const int quad = lane >> 4;
    const int segbase = blockIdx.x * SEGW;

    __shared__ __align__(16) unsigned short hlds[SEGW * HSTR];  // 1.15 KB
    __shared__ int sb[SEGW + 1];

    // --- segment bounds: 9 parallel binary searches (index sorted) ---
    if (lane <= SEGW) {
        int tgt = segbase + lane; tgt = tgt < B ? tgt : B;
        int lo = 0, hi = N;
        while (lo < hi) { int m = (lo + hi) >> 1; if (index[m] < tgt) lo = m + 1; else hi = m; }
        sb[lane] = lo;
    }
    for (int i = lane; i < SEGW * HSTR / 2; i += 64) ((int*)hlds)[i] = 0;
    __syncthreads();

    // --- full weight matrices in registers, pre-scaled; bias as C-seed ---
    bf16x8 wi[4][4][2], wh[4][4][2];      // [gate][coltile][ktile], 256 VGPR
    float bsv[4][4];
#pragma unroll
    for (int g = 0; g < 4; ++g) {
        const float sc = (g == 2) ? (-2.0f * L2E) : (-L2E);
#pragma unroll
        for (int ct = 0; ct < 4; ++ct) {
            const int row = g * HDIM + ct * 16 + l15;
            bsv[g][ct] = sc * (bih[row] + bhh[row]);
#pragma unroll
            for (int kt = 0; kt < 2; ++kt) {
                const f32x4* pi = (const f32x4*)(Wih + (size_t)row * HDIM + kt * 32 + quad * 8);
                const f32x4* ph = (const f32x4*)(Whh + (size_t)row * HDIM + kt * 32 + quad * 8);
                wi[g][ct][kt] = pack8(pi[0] * sc, pi[1] * sc);
                wh[g][ct][kt] = pack8(ph[0] * sc, ph[1] * sc);
            }
        }
    }

    // A-row seg alias for this lane's row m=l15: rows {4k,4k+1} real -> seg
    // {2k,2k+1}; rows {4k+2,4k+3} alias the same pair.
    const int sA   = ((l15 >> 2) << 1) | (l15 & 1);
    const int sstA = sb[sA];
    int lenA = sb[sA + 1] - sstA; lenA = lenA < MAXLEN ? lenA : MAXLEN;

    int len2[2];
#pragma unroll
    for (int r = 0; r < 2; ++r) {
        const int s = quad * 2 + r;
        int l = sb[s + 1] - sb[s];
        len2[r] = l < MAXLEN ? l : MAXLEN;
    }
    int lmax = 0;
#pragma unroll
    for (int i = 0; i < SEGW; ++i) {
        int l = sb[i + 1] - sb[i]; l = l < MAXLEN ? l : MAXLEN;
        lmax = l > lmax ? l : lmax;
    }
    lmax = __builtin_amdgcn_readfirstlane(lmax);

    // x prefetch: per lane 16 floats (k 0..31 and 32..63 slices of its seg
    // row), 2 steps ahead in registers; frozen/overrun steps clamp to the
    // last valid row (result discarded by the freeze predicate).
    f32x4 pfA[4], pfB[4];
#define XLOAD(PF_, T_) {                                                        \
        int ct_ = (T_); ct_ = lenA > 0 ? (ct_ < lenA ? ct_ : lenA - 1) : 0;     \
        int row_ = sstA + ct_; row_ = row_ < N - 1 ? row_ : N - 1;              \
        const f32x4* p_ = (const f32x4*)(x + (size_t)row_ * HDIM + quad * 8);   \
        PF_[0] = p_[0]; PF_[1] = p_[1];                                         \
        const f32x4* q_ = (const f32x4*)(x + (size_t)row_ * HDIM + 32 + quad * 8); \
        PF_[2] = q_[0]; PF_[3] = q_[1]; }

    float c2[4][2] = {{0, 0}, {0, 0}, {0, 0}, {0, 0}};
    float h2[4][2] = {{0, 0}, {0, 0}, {0, 0}, {0, 0}};

    // Per step: read h(t-1) A-frags (same-wave DS order guarantees prev
    // writes land first), issue next x loads, 32 x-MFMAs (bias-seeded),
    // 32 h-MFMAs, 8 cells of gate math, 8 b16 h-writes. No barrier.
#define STEP(T_, PF_) {                                                         \
        const int t_ = (T_);                                                    \
        bf16x8 xa0 = pack8(PF_[0], PF_[1]);                                     \
        bf16x8 xa1 = pack8(PF_[2], PF_[3]);                                     \
        bf16x8 ha0 = *(const bf16x8*)(hlds + sA * HSTR + quad * 8);             \
        bf16x8 ha1 = *(const bf16x8*)(hlds + sA * HSTR + 32 + quad * 8);        \
        XLOAD(PF_, t_ + 2);                                                     \
        f32x4 acc[4][4];                                                        \
        _Pragma("unroll") for (int g = 0; g < 4; ++g)                           \
        _Pragma("unroll") for (int ct = 0; ct < 4; ++ct) {                      \
            f32x4 seed = {bsv[g][ct], bsv[g][ct], bsv[g][ct], bsv[g][ct]};      \
            f32x4 a_ = __builtin_amdgcn_mfma_f32_16x16x32_bf16(xa0, wi[g][ct][0], seed, 0, 0, 0); \
            acc[g][ct] = __builtin_amdgcn_mfma_f32_16x16x32_bf16(xa1, wi[g][ct][1], a_, 0, 0, 0); \
        }                                                                       \
        _Pragma("unroll") for (int g = 0; g < 4; ++g)                           \
        _Pragma("unroll") for (int ct = 0; ct < 4; ++ct) {                      \
            f32x4 a_ = __builtin_amdgcn_mfma_f32_16x16x32_bf16(ha0, wh[g][ct][0], acc[g][ct], 0, 0, 0); \
            acc[g][ct] = __builtin_amdgcn_mfma_f32_16x16x32_bf16(ha1, wh[g][ct][1], a_, 0, 0, 0); \
        }                                                                       \
        _Pragma("unroll") for (int ct = 0; ct < 4; ++ct)                        \
        _Pragma("unroll") for (int r = 0; r < 2; ++r) {                         \
            float gi = sig_pre (acc[0][ct][r]);                                 \
            float gf = sig_pre (acc[1][ct][r]);                                 \
            float gg = tanh_pre(acc[2][ct][r]);                                 \
            float go = sig_pre (acc[3][ct][r]);                                 \
            float cn = fmaf(gf, c2[ct][r], gi * gg);                            \
            float hn = go * tanh_p(cn);                                         \
            const bool up = t_ < len2[r];                                       \
            c2[ct][r] = up ? cn : c2[ct][r];                                    \
            h2[ct][r] = up ? hn : h2[ct][r];                                    \
            hlds[(quad * 2 + r) * HSTR + ct * 16 + l15] =                       \
                (unsigned short)cvtpk(h2[ct][r], h2[ct][r]);                    \
        } }

    if (lmax > 0) {
        XLOAD(pfA, 0);
        XLOAD(pfB, 1);
        for (int t = 0; t < lmax; t += 2) {
            STEP(t, pfA);
            if (t + 1 < lmax) STEP(t + 1, pfB);
        }
    }

#pragma unroll
    for (int r = 0; r < 2; ++r) {
        const int seg = segbase + quad * 2 + r;
        if (seg < B) {
#pragma unroll
            for (int ct = 0; ct < 4; ++ct)
                out[(size_t)seg * HDIM + ct * 16 + l15] = h2[ct][r];
        }
    }
#undef XLOAD
#undef STEP
}

extern "C" void kernel_launch(void* const* d_in, const int* in_sizes, int n_in,
                              void* d_out, int out_size, void* d_ws, size_t ws_size,
                              hipStream_t stream) {
    const float* x     = (const float*)d_in[0];
    const float* Wih   = (const float*)d_in[1];
    const float* Whh   = (const float*)d_in[2];
    const float* bih   = (const float*)d_in[3];
    const float* bhh   = (const float*)d_in[4];
    const int*   index = (const int*)d_in[5];

    const int N = in_sizes[5];
    const int B = out_size / HDIM;   // 8192

    const int nblocks = (B + SEGW - 1) / SEGW;   // 1024
    lstm_wave_kernel<<<nblocks, 64, 0, stream>>>(x, Wih, Whh, bih, bhh, index,
                                                 (float*)d_out, N, B);
}